// Round 15
// baseline (171.269 us; speedup 1.0000x reference)
//
#include <hip/hip_runtime.h>
#include <hip/hip_fp16.h>
#include <math.h>

#define N_NODES 100000
#define N_EDGES 3200000

// Bucketed counting sort: 512 nodes per bucket, 256 partition blocks.
// Run length per (block,bucket) = 12500/196 ~ 64 edges = 256B -> low
// write-allocate amplification in part2.
#define NPBC  512
#define NBC   196            // ceil(100000/512)
#define KB2   256            // partition blocks
#define CH2   12500          // edges per partition block (N_EDGES / KB2)

// h2 row stride in halfs: 24B rows (11 values + 1 pad), 8B-aligned.
// Table = 2.4MB, L2-resident. Row load = uint4+uint2.
#define HS    12

__device__ __forceinline__ float gelu_tanh(float x) {
    // jax.nn.gelu default approximate=True (tanh form)
    const float c = 0.7978845608028654f;  // sqrt(2/pi)
    float t = tanhf(c * (x + 0.044715f * x * x * x));
    return 0.5f * x * (1.0f + t);
}

// Per-block int64/int32 layout detection: under little-endian int64 with
// values in [0,1e5), every odd dword of the first 64 pairs is 0; under int32
// those dwords are random src ids. The 512B probed bytes are L2-resident after
// the first block touches them. Result broadcast through LDS.
__device__ __forceinline__ int detect_flag(const void* ei, int t, int* sflag) {
    if (t < 64) {
        unsigned int v = ((const unsigned int*)ei)[2 * t + 1];
        unsigned long long m = __ballot(v != 0u);
        if (t == 0) *sflag = (m != 0ull) ? 1 : 0;  // 1 => int32 layout
    }
    __syncthreads();
    return *sflag;
}

__device__ __forceinline__ int load_idx(const void* ei, int f, size_t pos) {
    if (f) return ((const int*)ei)[pos];
    return (int)((const long long*)ei)[pos];
}

// Pass A: per-block bucket histogram -> bcnt[k*NBC + b] (coalesced writeback).
__global__ void cnt_kernel(const void* __restrict__ ei, int* __restrict__ bcnt) {
    __shared__ int lcnt[NBC];
    __shared__ int sflag;
    int k = blockIdx.x, t = threadIdx.x;
    int f = detect_flag(ei, t, &sflag);
    for (int b = t; b < NBC; b += 256) lcnt[b] = 0;
    __syncthreads();
    int lo = k * CH2, hi = min(lo + CH2, N_EDGES);
    for (int e = lo + t; e < hi; e += 256) {
        int d = load_idx(ei, f, (size_t)N_EDGES + e);
        atomicAdd(&lcnt[d >> 9], 1);
    }
    __syncthreads();
    for (int b = t; b < NBC; b += 256) bcnt[(size_t)k * NBC + b] = lcnt[b];
}

// Pass B (merged bprefix+bscan): single block, 256 threads. Thread t (<NBC)
// owns bucket t: serial exclusive prefix over the KB2 block counts (loads are
// coalesced across threads at each k), then an LDS scan over the 196 bucket
// totals -> bbase/tot; off[N] = E.
__global__ void prefix_kernel(int* __restrict__ bcnt, int* __restrict__ tot,
                              int* __restrict__ bbase, int* __restrict__ off) {
    __shared__ int sh[256];
    int t = threadIdx.x;
    int run = 0;
    if (t < NBC) {
#pragma unroll 4
        for (int k = 0; k < KB2; k++) {
            int v = bcnt[(size_t)k * NBC + t];
            bcnt[(size_t)k * NBC + t] = run;
            run += v;
        }
    }
    sh[t] = (t < NBC) ? run : 0;
    __syncthreads();
    int val = sh[t];
    for (int o = 1; o < 256; o <<= 1) {
        int add = (t >= o) ? sh[t - o] : 0;
        __syncthreads();
        val += add;
        sh[t] = val;
        __syncthreads();
    }
    if (t < NBC) {
        tot[t] = run;
        bbase[t] = val - run;  // exclusive
    }
    if (t == 0) off[N_NODES] = N_EDGES;
}

// Pass C: place each edge in its block's pre-claimed range (no global atomics).
// Packed entry = src | local_dst<<17  (src 17 bits, local 9 bits).
__global__ void part2_kernel(const void* __restrict__ ei, const int* __restrict__ boff,
                             const int* __restrict__ bbase, int* __restrict__ btmp) {
    __shared__ int lcnt[NBC];
    __shared__ int lbase[NBC];
    __shared__ int sflag;
    int k = blockIdx.x, t = threadIdx.x;
    int f = detect_flag(ei, t, &sflag);
    for (int b = t; b < NBC; b += 256) {
        lcnt[b] = 0;
        lbase[b] = bbase[b] + boff[(size_t)k * NBC + b];  // coalesced read
    }
    __syncthreads();
    int lo = k * CH2, hi = min(lo + CH2, N_EDGES);
    for (int e = lo + t; e < hi; e += 256) {
        int s = load_idx(ei, f, e);
        int d = load_idx(ei, f, (size_t)N_EDGES + e);
        int b = d >> 9;
        int pos = atomicAdd(&lcnt[b], 1);
        btmp[lbase[b] + pos] = s | ((d & (NPBC - 1)) << 17);
    }
}

// Pass D (+fused layer-1 node transform): one block per bucket (512 threads =
// 512 local nodes). LDS histogram + scan -> off/dinv; scatter the bucket's csr
// segment; then thread t computes h2a[node] = fp16(dinv * (X[node] @ W1)).
__global__ void build2_kernel(const int* __restrict__ tot, const int* __restrict__ bbase,
                              const int* __restrict__ btmp, int* __restrict__ csr,
                              int* __restrict__ off, float* __restrict__ dinv,
                              const float* __restrict__ X, const float* __restrict__ W,
                              __half* __restrict__ h2) {
    __shared__ int lcnt[NPBC];
    __shared__ int lcur[NPBC];
    __shared__ int ssc[NPBC];
    int b = blockIdx.x;
    int t = threadIdx.x;   // 0..511, == local node id
    int cnt = tot[b];
    int base = bbase[b];
    lcnt[t] = 0;
    __syncthreads();
    const int* bt = btmp + base;
    for (int i = t; i < cnt; i += NPBC) atomicAdd(&lcnt[bt[i] >> 17], 1);
    __syncthreads();
    int c = lcnt[t];
    ssc[t] = c;
    __syncthreads();
    int val = c;
    for (int o = 1; o < NPBC; o <<= 1) {
        int add = (t >= o) ? ssc[t - o] : 0;
        __syncthreads();
        val += add;
        ssc[t] = val;
        __syncthreads();
    }
    int excl = val - c;
    lcur[t] = excl;
    int node = b * NPBC + t;
    float di = rsqrtf((float)c + 1.0f);  // +1 = appended self-loop
    if (node < N_NODES) {
        off[node] = base + excl;
        dinv[node] = di;
    }
    __syncthreads();
    for (int i = t; i < cnt; i += NPBC) {
        int e = bt[i];
        int p = atomicAdd(&lcur[e >> 17], 1);
        csr[base + p] = e & 0x1FFFF;
    }
    // Fused node1: layer-1 pre-propagation for this block's nodes.
    if (node < N_NODES) {
        float x[11];
#pragma unroll
        for (int i = 0; i < 11; i++) x[i] = X[(size_t)node * 11 + i];
#pragma unroll
        for (int j = 0; j < 11; j++) {
            float a = 0.0f;
#pragma unroll
            for (int i = 0; i < 11; i++) a += x[i] * W[i * 11 + j];
            h2[(size_t)node * HS + j] = __float2half(di * a);
        }
        h2[(size_t)node * HS + 11] = __float2half(0.0f);
    }
}

// Accumulate one fp16 h2 row (stride 12 halfs = 24B, 8B-aligned) into
// a[0..10]. Two memory requests: 16B (halfs 0..7) + 8B (halfs 8..11).
__device__ __forceinline__ void acc_row(const __half* __restrict__ h2, int n, float* a) {
    const __half* r = h2 + (size_t)n * HS;
    uint4 u = *(const uint4*)r;          // dwordx4 (dword alignment suffices)
    uint2 v = *(const uint2*)(r + 8);
    union { unsigned int u; __half2 h; } cv;
    float2 f;
    cv.u = u.x; f = __half22float2(cv.h); a[0] += f.x; a[1] += f.y;
    cv.u = u.y; f = __half22float2(cv.h); a[2] += f.x; a[3] += f.y;
    cv.u = u.z; f = __half22float2(cv.h); a[4] += f.x; a[5] += f.y;
    cv.u = u.w; f = __half22float2(cv.h); a[6] += f.x; a[7] += f.y;
    cv.u = v.x; f = __half22float2(cv.h); a[8] += f.x; a[9] += f.y;
    cv.u = v.y; f = __half22float2(cv.h); a[10] += f.x;
}

// Gather a node's neighbor rows with software-pipelined index prefetch.
// 8 lanes per node (p = lane phase 0..7), stride-8 edge walk.
__device__ __forceinline__ void gather8(const int* __restrict__ csr, int lo, int hi, int p,
                                        const __half* __restrict__ h2in, float* a) {
    int e = lo + p;
    if (e >= hi) return;
    int s = csr[e];
    for (e += 8; e < hi; e += 8) {
        int s_next = csr[e];
        acc_row(h2in, s, a);
        s = s_next;
    }
    acc_row(h2in, s, a);
}

// Fused gather + finalize + gelu + next-layer GEMM. 8 lanes per node.
template <int OUT>
__global__ void mid_kernel(const int* __restrict__ off, const int* __restrict__ csr,
                           const __half* __restrict__ h2in, const float* __restrict__ bias,
                           const float* __restrict__ W, const float* __restrict__ dinv,
                           __half* __restrict__ h2out) {
    int tid = blockIdx.x * blockDim.x + threadIdx.x;
    int n = tid >> 3;
    int p = tid & 7;
    if (n >= N_NODES) return;
    int lo = off[n], hi = off[n + 1];
    float a[11];
#pragma unroll
    for (int i = 0; i < 11; i++) a[i] = 0.0f;
    if (p == 0) acc_row(h2in, n, a);  // self-loop term
    gather8(csr, lo, hi, p, h2in, a);
#pragma unroll
    for (int i = 0; i < 11; i++) {
        a[i] += __shfl_xor(a[i], 1);
        a[i] += __shfl_xor(a[i], 2);
        a[i] += __shfl_xor(a[i], 4);
    }
    float di = dinv[n];
    float t[11];
#pragma unroll
    for (int i = 0; i < 11; i++) t[i] = gelu_tanh(di * a[i] + bias[i]);
    // 12 output slots over 8 lanes: j = p (all) and j = p+8 (p<4).
#pragma unroll
    for (int j0 = 0; j0 < 2; j0++) {
        int j = p + 8 * j0;
        if (j >= HS) continue;
        float o = 0.0f;
        if (j < OUT) {
            float acc = 0.0f;
#pragma unroll
            for (int i = 0; i < 11; i++) acc += t[i] * W[i * OUT + j];
            o = di * acc;
        }
        h2out[(size_t)n * HS + j] = __float2half(o);
    }
}

// Final layer: gather + finalize + log_softmax (10 classes). 8 lanes per node.
__global__ void final_kernel(const int* __restrict__ off, const int* __restrict__ csr,
                             const __half* __restrict__ h2in, const float* __restrict__ bias,
                             const float* __restrict__ dinv, float* __restrict__ out) {
    int tid = blockIdx.x * blockDim.x + threadIdx.x;
    int n = tid >> 3;
    int p = tid & 7;
    if (n >= N_NODES) return;
    int lo = off[n], hi = off[n + 1];
    float a[11];
#pragma unroll
    for (int i = 0; i < 11; i++) a[i] = 0.0f;
    if (p == 0) acc_row(h2in, n, a);
    gather8(csr, lo, hi, p, h2in, a);
#pragma unroll
    for (int i = 0; i < 10; i++) {
        a[i] += __shfl_xor(a[i], 1);
        a[i] += __shfl_xor(a[i], 2);
        a[i] += __shfl_xor(a[i], 4);
    }
    float di = dinv[n];
    float t[10];
    float m = -1e30f;
#pragma unroll
    for (int j = 0; j < 10; j++) {
        t[j] = di * a[j] + bias[j];
        m = fmaxf(m, t[j]);
    }
    float s = 0.0f;
#pragma unroll
    for (int j = 0; j < 10; j++) s += expf(t[j] - m);
    float ls = logf(s);
    for (int j = p; j < 10; j += 8) out[(size_t)n * 10 + j] = t[j] - m - ls;
}

extern "C" void kernel_launch(void* const* d_in, const int* in_sizes, int n_in,
                              void* d_out, int out_size, void* d_ws, size_t ws_size,
                              hipStream_t stream) {
    const float* X  = (const float*)d_in[0];
    const void*  ei = d_in[1];
    const float* W1 = (const float*)d_in[2];
    const float* b1 = (const float*)d_in[3];
    const float* W2 = (const float*)d_in[4];
    const float* b2 = (const float*)d_in[5];
    const float* W3 = (const float*)d_in[6];
    const float* b3 = (const float*)d_in[7];
    float* out = (float*)d_out;

    const size_t N = N_NODES;
    const size_t E = N_EDGES;
    // Workspace layout (regions kept 16B-aligned).
    __half* h2a = (__half*)d_ws;                // [HS*N] halfs (2.4 MB)
    __half* h2b = h2a + (size_t)HS * N;         // [HS*N] halfs
    int*   csr  = (int*)(h2b + (size_t)HS * N); // [E]
    int*   btmp = csr + E;                      // [E]
    int*   bcnt = btmp + E;                     // [KB2*NBC] (becomes boff in place)
    int*   tot  = bcnt + (size_t)KB2 * NBC;     // [NBC+4 pad]
    int*   bbase= tot + NBC + 4;                // [NBC+4 pad]
    int*   off  = bbase + NBC + 4;              // [N+4]
    float* dinv = (float*)(off + N + 4);        // [N]

    const int gb8 = (8 * N_NODES + 255) / 256;

    cnt_kernel<<<KB2, 256, 0, stream>>>(ei, bcnt);
    prefix_kernel<<<1, 256, 0, stream>>>(bcnt, tot, bbase, off);
    part2_kernel<<<KB2, 256, 0, stream>>>(ei, bcnt, bbase, btmp);
    build2_kernel<<<NBC, NPBC, 0, stream>>>(tot, bbase, btmp, csr, off, dinv,
                                            X, W1, h2a);
    mid_kernel<11><<<gb8, 256, 0, stream>>>(off, csr, h2a, b1, W2, dinv, h2b);
    mid_kernel<10><<<gb8, 256, 0, stream>>>(off, csr, h2b, b2, W3, dinv, h2a);
    final_kernel<<<gb8, 256, 0, stream>>>(off, csr, h2a, b3, dinv, out);
}

// Round 16
// 156.310 us; speedup vs baseline: 1.0957x; 1.0957x over previous
//
#include <hip/hip_runtime.h>
#include <hip/hip_fp16.h>
#include <math.h>

#define N_NODES 100000
#define N_EDGES 3200000

// Bucketed counting sort: 512 nodes per bucket, 256 partition blocks.
// Run length per (block,bucket) = 12500/196 ~ 64 edges = 256B -> low
// write-allocate amplification in part2.
#define NPBC  512
#define NBC   196            // ceil(100000/512)
#define KB2   256            // partition blocks
#define CH2   12500          // edges per partition block (N_EDGES / KB2)

// h2 row stride in halfs: 24B rows (11 values + 1 pad), 8B-aligned.
// Table = 2.4MB, L2-resident. Row load = uint4+uint2.
#define HS    12

__device__ __forceinline__ float gelu_tanh(float x) {
    // jax.nn.gelu default approximate=True (tanh form)
    const float c = 0.7978845608028654f;  // sqrt(2/pi)
    float t = tanhf(c * (x + 0.044715f * x * x * x));
    return 0.5f * x * (1.0f + t);
}

// Per-block int64/int32 layout detection: under little-endian int64 with
// values in [0,1e5), every odd dword of the first 64 pairs is 0; under int32
// those dwords are random src ids. The 512B probed are L2-resident after the
// first block touches them. Result broadcast through LDS.
__device__ __forceinline__ int detect_flag(const void* ei, int t, int* sflag) {
    if (t < 64) {
        unsigned int v = ((const unsigned int*)ei)[2 * t + 1];
        unsigned long long m = __ballot(v != 0u);
        if (t == 0) *sflag = (m != 0ull) ? 1 : 0;  // 1 => int32 layout
    }
    __syncthreads();
    return *sflag;
}

__device__ __forceinline__ int load_idx(const void* ei, int f, size_t pos) {
    if (f) return ((const int*)ei)[pos];
    return (int)((const long long*)ei)[pos];
}

// Pass A: per-block bucket histogram -> bcnt[k*NBC + b] (coalesced writeback).
__global__ void cnt_kernel(const void* __restrict__ ei, int* __restrict__ bcnt) {
    __shared__ int lcnt[NBC];
    __shared__ int sflag;
    int k = blockIdx.x, t = threadIdx.x;
    int f = detect_flag(ei, t, &sflag);
    for (int b = t; b < NBC; b += 256) lcnt[b] = 0;
    __syncthreads();
    int lo = k * CH2, hi = min(lo + CH2, N_EDGES);
    for (int e = lo + t; e < hi; e += 256) {
        int d = load_idx(ei, f, (size_t)N_EDGES + e);
        atomicAdd(&lcnt[d >> 9], 1);
    }
    __syncthreads();
    for (int b = t; b < NBC; b += 256) bcnt[(size_t)k * NBC + b] = lcnt[b];
}

// Pass B1: per-bucket exclusive prefix over the KB2 blocks — one WAVE per
// bucket, 4 entries per lane, shfl_up wave scan. In-place; tot[b] = sum.
__global__ void bprefix_kernel(int* __restrict__ bcnt, int* __restrict__ tot) {
    int gid = blockIdx.x * blockDim.x + threadIdx.x;
    int w = gid >> 6;           // bucket
    int l = gid & 63;           // lane
    if (w >= NBC) return;
    int v[4];
    int s = 0;
#pragma unroll
    for (int i = 0; i < 4; i++) {
        v[i] = bcnt[(size_t)(l * 4 + i) * NBC + w];
        s += v[i];
    }
    int scan = s;
#pragma unroll
    for (int o = 1; o < 64; o <<= 1) {
        int x = __shfl_up(scan, o);
        if (l >= o) scan += x;
    }
    int run = scan - s;  // exclusive over lanes
#pragma unroll
    for (int i = 0; i < 4; i++) {
        bcnt[(size_t)(l * 4 + i) * NBC + w] = run;
        run += v[i];
    }
    if (l == 63) tot[w] = scan;
}

// Pass B2: exclusive scan over bucket totals -> bbase; off[N] = E.
__global__ void bscan_kernel(const int* __restrict__ tot, int* __restrict__ bbase,
                             int* __restrict__ off) {
    __shared__ int sh[256];
    int t = threadIdx.x;
    int v = (t < NBC) ? tot[t] : 0;
    sh[t] = v;
    __syncthreads();
    int val = v;
    for (int o = 1; o < 256; o <<= 1) {
        int add = (t >= o) ? sh[t - o] : 0;
        __syncthreads();
        val += add;
        sh[t] = val;
        __syncthreads();
    }
    if (t < NBC) bbase[t] = val - v;
    if (t == NBC - 1) off[N_NODES] = val;  // == N_EDGES
}

// Pass C: place each edge in its block's pre-claimed range (no global atomics).
// Packed entry = src | local_dst<<17  (src 17 bits, local 9 bits).
__global__ void part2_kernel(const void* __restrict__ ei, const int* __restrict__ boff,
                             const int* __restrict__ bbase, int* __restrict__ btmp) {
    __shared__ int lcnt[NBC];
    __shared__ int lbase[NBC];
    __shared__ int sflag;
    int k = blockIdx.x, t = threadIdx.x;
    int f = detect_flag(ei, t, &sflag);
    for (int b = t; b < NBC; b += 256) {
        lcnt[b] = 0;
        lbase[b] = bbase[b] + boff[(size_t)k * NBC + b];  // coalesced read
    }
    __syncthreads();
    int lo = k * CH2, hi = min(lo + CH2, N_EDGES);
    for (int e = lo + t; e < hi; e += 256) {
        int s = load_idx(ei, f, e);
        int d = load_idx(ei, f, (size_t)N_EDGES + e);
        int b = d >> 9;
        int pos = atomicAdd(&lcnt[b], 1);
        btmp[lbase[b] + pos] = s | ((d & (NPBC - 1)) << 17);
    }
}

// Pass D (+fused layer-1 node transform): one block per bucket (512 threads =
// 512 local nodes). LDS histogram + scan -> off/dinv; scatter the bucket's csr
// segment; then thread t computes h2a[node] = fp16(dinv * (X[node] @ W1)).
__global__ void build2_kernel(const int* __restrict__ tot, const int* __restrict__ bbase,
                              const int* __restrict__ btmp, int* __restrict__ csr,
                              int* __restrict__ off, float* __restrict__ dinv,
                              const float* __restrict__ X, const float* __restrict__ W,
                              __half* __restrict__ h2) {
    __shared__ int lcnt[NPBC];
    __shared__ int lcur[NPBC];
    __shared__ int ssc[NPBC];
    int b = blockIdx.x;
    int t = threadIdx.x;   // 0..511, == local node id
    int cnt = tot[b];
    int base = bbase[b];
    lcnt[t] = 0;
    __syncthreads();
    const int* bt = btmp + base;
    for (int i = t; i < cnt; i += NPBC) atomicAdd(&lcnt[bt[i] >> 17], 1);
    __syncthreads();
    int c = lcnt[t];
    ssc[t] = c;
    __syncthreads();
    int val = c;
    for (int o = 1; o < NPBC; o <<= 1) {
        int add = (t >= o) ? ssc[t - o] : 0;
        __syncthreads();
        val += add;
        ssc[t] = val;
        __syncthreads();
    }
    int excl = val - c;
    lcur[t] = excl;
    int node = b * NPBC + t;
    float di = rsqrtf((float)c + 1.0f);  // +1 = appended self-loop
    if (node < N_NODES) {
        off[node] = base + excl;
        dinv[node] = di;
    }
    __syncthreads();
    for (int i = t; i < cnt; i += NPBC) {
        int e = bt[i];
        int p = atomicAdd(&lcur[e >> 17], 1);
        csr[base + p] = e & 0x1FFFF;
    }
    // Fused node1: layer-1 pre-propagation for this block's nodes.
    if (node < N_NODES) {
        float x[11];
#pragma unroll
        for (int i = 0; i < 11; i++) x[i] = X[(size_t)node * 11 + i];
#pragma unroll
        for (int j = 0; j < 11; j++) {
            float a = 0.0f;
#pragma unroll
            for (int i = 0; i < 11; i++) a += x[i] * W[i * 11 + j];
            h2[(size_t)node * HS + j] = __float2half(di * a);
        }
        h2[(size_t)node * HS + 11] = __float2half(0.0f);
    }
}

// Accumulate one fp16 h2 row (stride 12 halfs = 24B, 8B-aligned) into
// a[0..10]. Two memory requests: 16B (halfs 0..7) + 8B (halfs 8..11).
__device__ __forceinline__ void acc_row(const __half* __restrict__ h2, int n, float* a) {
    const __half* r = h2 + (size_t)n * HS;
    uint4 u = *(const uint4*)r;          // dwordx4 (dword alignment suffices)
    uint2 v = *(const uint2*)(r + 8);
    union { unsigned int u; __half2 h; } cv;
    float2 f;
    cv.u = u.x; f = __half22float2(cv.h); a[0] += f.x; a[1] += f.y;
    cv.u = u.y; f = __half22float2(cv.h); a[2] += f.x; a[3] += f.y;
    cv.u = u.z; f = __half22float2(cv.h); a[4] += f.x; a[5] += f.y;
    cv.u = u.w; f = __half22float2(cv.h); a[6] += f.x; a[7] += f.y;
    cv.u = v.x; f = __half22float2(cv.h); a[8] += f.x; a[9] += f.y;
    cv.u = v.y; f = __half22float2(cv.h); a[10] += f.x;
}

// Gather a node's neighbor rows with software-pipelined index prefetch.
// 16 lanes per node (p = lane phase 0..15), stride-16 edge walk: mean-degree
// 32 graph -> dependent-gather chain of ~2 per lane, 2x the waves for TLP.
__device__ __forceinline__ void gather16(const int* __restrict__ csr, int lo, int hi, int p,
                                         const __half* __restrict__ h2in, float* a) {
    int e = lo + p;
    if (e >= hi) return;
    int s = csr[e];
    for (e += 16; e < hi; e += 16) {
        int s_next = csr[e];
        acc_row(h2in, s, a);
        s = s_next;
    }
    acc_row(h2in, s, a);
}

// Fused gather + finalize + gelu + next-layer GEMM. 16 lanes per node.
template <int OUT>
__global__ void mid_kernel(const int* __restrict__ off, const int* __restrict__ csr,
                           const __half* __restrict__ h2in, const float* __restrict__ bias,
                           const float* __restrict__ W, const float* __restrict__ dinv,
                           __half* __restrict__ h2out) {
    int tid = blockIdx.x * blockDim.x + threadIdx.x;
    int n = tid >> 4;
    int p = tid & 15;
    if (n >= N_NODES) return;
    int lo = off[n], hi = off[n + 1];
    float a[11];
#pragma unroll
    for (int i = 0; i < 11; i++) a[i] = 0.0f;
    if (p == 0) acc_row(h2in, n, a);  // self-loop term
    gather16(csr, lo, hi, p, h2in, a);
#pragma unroll
    for (int i = 0; i < 11; i++) {
        a[i] += __shfl_xor(a[i], 1);
        a[i] += __shfl_xor(a[i], 2);
        a[i] += __shfl_xor(a[i], 4);
        a[i] += __shfl_xor(a[i], 8);
    }
    float di = dinv[n];
    float t[11];
#pragma unroll
    for (int i = 0; i < 11; i++) t[i] = gelu_tanh(di * a[i] + bias[i]);
    // 12 output slots over 16 lanes: j = p for p < HS.
    if (p < HS) {
        float o = 0.0f;
        if (p < OUT) {
            float acc = 0.0f;
#pragma unroll
            for (int i = 0; i < 11; i++) acc += t[i] * W[i * OUT + p];
            o = di * acc;
        }
        h2out[(size_t)n * HS + p] = __float2half(o);
    }
}

// Final layer: gather + finalize + log_softmax (10 classes). 16 lanes per node.
__global__ void final_kernel(const int* __restrict__ off, const int* __restrict__ csr,
                             const __half* __restrict__ h2in, const float* __restrict__ bias,
                             const float* __restrict__ dinv, float* __restrict__ out) {
    int tid = blockIdx.x * blockDim.x + threadIdx.x;
    int n = tid >> 4;
    int p = tid & 15;
    if (n >= N_NODES) return;
    int lo = off[n], hi = off[n + 1];
    float a[11];
#pragma unroll
    for (int i = 0; i < 11; i++) a[i] = 0.0f;
    if (p == 0) acc_row(h2in, n, a);
    gather16(csr, lo, hi, p, h2in, a);
#pragma unroll
    for (int i = 0; i < 10; i++) {
        a[i] += __shfl_xor(a[i], 1);
        a[i] += __shfl_xor(a[i], 2);
        a[i] += __shfl_xor(a[i], 4);
        a[i] += __shfl_xor(a[i], 8);
    }
    float di = dinv[n];
    float t[10];
    float m = -1e30f;
#pragma unroll
    for (int j = 0; j < 10; j++) {
        t[j] = di * a[j] + bias[j];
        m = fmaxf(m, t[j]);
    }
    float s = 0.0f;
#pragma unroll
    for (int j = 0; j < 10; j++) s += expf(t[j] - m);
    float ls = logf(s);
    if (p < 10) out[(size_t)n * 10 + p] = t[p] - m - ls;
}

extern "C" void kernel_launch(void* const* d_in, const int* in_sizes, int n_in,
                              void* d_out, int out_size, void* d_ws, size_t ws_size,
                              hipStream_t stream) {
    const float* X  = (const float*)d_in[0];
    const void*  ei = d_in[1];
    const float* W1 = (const float*)d_in[2];
    const float* b1 = (const float*)d_in[3];
    const float* W2 = (const float*)d_in[4];
    const float* b2 = (const float*)d_in[5];
    const float* W3 = (const float*)d_in[6];
    const float* b3 = (const float*)d_in[7];
    float* out = (float*)d_out;

    const size_t N = N_NODES;
    const size_t E = N_EDGES;
    // Workspace layout (regions kept 16B-aligned).
    __half* h2a = (__half*)d_ws;                // [HS*N] halfs (2.4 MB)
    __half* h2b = h2a + (size_t)HS * N;         // [HS*N] halfs
    int*   csr  = (int*)(h2b + (size_t)HS * N); // [E]
    int*   btmp = csr + E;                      // [E]
    int*   bcnt = btmp + E;                     // [KB2*NBC] (becomes boff in place)
    int*   tot  = bcnt + (size_t)KB2 * NBC;     // [NBC+4 pad]
    int*   bbase= tot + NBC + 4;                // [NBC+4 pad]
    int*   off  = bbase + NBC + 4;              // [N+4]
    float* dinv = (float*)(off + N + 4);        // [N]

    const int gb16 = (16 * N_NODES + 255) / 256;
    const int pb = (NBC * 64 + 255) / 256;      // bprefix: one wave per bucket

    cnt_kernel<<<KB2, 256, 0, stream>>>(ei, bcnt);
    bprefix_kernel<<<pb, 256, 0, stream>>>(bcnt, tot);
    bscan_kernel<<<1, 256, 0, stream>>>(tot, bbase, off);
    part2_kernel<<<KB2, 256, 0, stream>>>(ei, bcnt, bbase, btmp);
    build2_kernel<<<NBC, NPBC, 0, stream>>>(tot, bbase, btmp, csr, off, dinv,
                                            X, W1, h2a);
    mid_kernel<11><<<gb16, 256, 0, stream>>>(off, csr, h2a, b1, W2, dinv, h2b);
    mid_kernel<10><<<gb16, 256, 0, stream>>>(off, csr, h2b, b2, W3, dinv, h2a);
    final_kernel<<<gb16, 256, 0, stream>>>(off, csr, h2a, b3, dinv, out);
}